// Round 1
// baseline (217.768 us; speedup 1.0000x reference)
//
#include <hip/hip_runtime.h>
#include <hip/hip_bf16.h>

#define B_ 2
#define T_ 4096
#define D_ 2048
#define H_ 4
#define NC 176            // combined proj cols: 128 q | 32 k | 4 w | 12 pad
#define ROWS (B_ * T_)    // 8192

typedef __attribute__((ext_vector_type(8))) short short8;   // 8 x bf16 (4 VGPRs)
typedef __attribute__((ext_vector_type(4))) float f32x4;
typedef __attribute__((ext_vector_type(4))) float float4v;

__device__ inline unsigned short f2bf(float f) {
  unsigned u = __float_as_uint(f);
  u += 0x7fffu + ((u >> 16) & 1u);   // RNE
  return (unsigned short)(u >> 16);
}
__device__ inline float bf2f(unsigned short s) {
  return __uint_as_float(((unsigned)s) << 16);
}

// ---------------- Kernel 1: pack [Wq; Wk; Ww; 0] into bf16 (176 x 2048) -----
__global__ __launch_bounds__(256) void pack_weights(const float* __restrict__ Wq,
                                                    const float* __restrict__ Ww,
                                                    const float* __restrict__ Wk,
                                                    unsigned short* __restrict__ Wcb) {
  int idx = blockIdx.x * 256 + threadIdx.x;
  if (idx >= NC * D_) return;
  int row = idx / D_, col = idx - row * D_;
  float v = 0.f;
  if (row < 128)       v = Wq[row * D_ + col];
  else if (row < 160)  v = Wk[(row - 128) * D_ + col];
  else if (row < 164)  v = Ww[(row - 160) * D_ + col];
  Wcb[idx] = f2bf(v);
}

// ---------------- Kernel 2: Cb(8192x176 bf16) = bf16(hs) @ Wcb^T ------------
// block = 256 thr (4 waves), each wave owns a 16-row m-tile, full K=2048,
// 11 n-tiles of 16 cols. A-frags: hs fp32 loaded + converted in-flight.
// B-frags: Wcb from L2 (720 KB, resident).
__global__ __launch_bounds__(256) void proj_kernel(const float* __restrict__ hs,
                                                   const unsigned short* __restrict__ Wcb,
                                                   unsigned short* __restrict__ Cb) {
  int wid  = threadIdx.x >> 6;
  int lane = threadIdx.x & 63;
  int lr = lane & 15, lo = lane >> 4;
  int row0 = blockIdx.x * 64 + wid * 16;

  const float*          ap = hs  + (size_t)(row0 + lr) * D_ + lo * 8;
  const unsigned short* bp = Wcb + (size_t)lr * D_ + lo * 8;

  f32x4 acc[11];
#pragma unroll
  for (int n = 0; n < 11; ++n) acc[n] = (f32x4){0.f, 0.f, 0.f, 0.f};

#pragma unroll 2
  for (int kk = 0; kk < D_; kk += 32) {
    float4v f0 = *(const float4v*)(ap + kk);
    float4v f1 = *(const float4v*)(ap + kk + 4);
    short8 a;
#pragma unroll
    for (int i = 0; i < 4; ++i) {
      a[i]     = (short)f2bf(f0[i]);
      a[i + 4] = (short)f2bf(f1[i]);
    }
#pragma unroll
    for (int n = 0; n < 11; ++n) {
      short8 b = *(const short8*)(bp + (size_t)n * 16 * D_ + kk);
      acc[n] = __builtin_amdgcn_mfma_f32_16x16x32_bf16(a, b, acc[n], 0, 0, 0);
    }
  }

  int crow = row0 + lo * 4;   // C/D: col = lane&15, row = (lane>>4)*4 + reg
#pragma unroll
  for (int n = 0; n < 11; ++n) {
    int col = n * 16 + lr;
#pragma unroll
    for (int r = 0; r < 4; ++r)
      Cb[(size_t)(crow + r) * NC + col] = f2bf(acc[n][r]);
  }
}

// ---------------- Kernel 3: out[b,t,s] = sum_h w[t,h]*relu(q[t,h,:].k[s,:]) -
// grid (S/128, T/128, B), block 256 (4 waves, 2x2 quadrants of 64x64).
__global__ __launch_bounds__(256) void score_kernel(const unsigned short* __restrict__ Cb,
                                                    float* __restrict__ out) {
  int b = blockIdx.z, tb = blockIdx.y, sb = blockIdx.x;
  int wid  = threadIdx.x >> 6;
  int lane = threadIdx.x & 63;
  int lr = lane & 15, lo = lane >> 4;
  int wm = wid >> 1, wn = wid & 1;
  int t_base = tb * 128 + wm * 64;
  int s_base = sb * 128 + wn * 64;

  const unsigned short* C = Cb + (size_t)b * T_ * NC;
  float* O = out + (size_t)b * T_ * T_;

  // B-frags: k is shared across heads -> only 4 (one per n-tile)
  short8 bf[4];
#pragma unroll
  for (int n = 0; n < 4; ++n)
    bf[n] = *(const short8*)(C + (size_t)(s_base + n * 16 + lr) * NC + 128 + lo * 8);

  const f32x4 zero = (f32x4){0.f, 0.f, 0.f, 0.f};

#pragma unroll
  for (int m = 0; m < 4; ++m) {
    int ta = t_base + m * 16;
    short8 af[H_];
#pragma unroll
    for (int h = 0; h < H_; ++h)
      af[h] = *(const short8*)(C + (size_t)(ta + lr) * NC + h * 32 + lo * 8);

    int tc = ta + lo * 4;
    float wv[4][H_];
#pragma unroll
    for (int r = 0; r < 4; ++r) {
      const unsigned short* wp = C + (size_t)(tc + r) * NC + 160;
#pragma unroll
      for (int h = 0; h < H_; ++h) wv[r][h] = bf2f(wp[h]);
    }

#pragma unroll
    for (int n = 0; n < 4; ++n) {
      f32x4 o = zero;
#pragma unroll
      for (int h = 0; h < H_; ++h) {
        f32x4 c = __builtin_amdgcn_mfma_f32_16x16x32_bf16(af[h], bf[n], zero, 0, 0, 0);
#pragma unroll
        for (int r = 0; r < 4; ++r) o[r] += wv[r][h] * fmaxf(c[r], 0.f);
      }
      int sc = s_base + n * 16 + lr;
#pragma unroll
      for (int r = 0; r < 4; ++r)
        O[(size_t)(tc + r) * T_ + sc] = o[r];
    }
  }
}

// ---------------------------------------------------------------------------
extern "C" void kernel_launch(void* const* d_in, const int* in_sizes, int n_in,
                              void* d_out, int out_size, void* d_ws, size_t ws_size,
                              hipStream_t stream) {
  const float* hs = (const float*)d_in[0];
  const float* Wq = (const float*)d_in[1];
  const float* Ww = (const float*)d_in[2];
  const float* Wk = (const float*)d_in[3];
  float* out = (float*)d_out;

  unsigned short* Wcb = (unsigned short*)d_ws;                      // 720,896 B
  unsigned short* Cb  = (unsigned short*)((char*)d_ws + (1 << 20)); // 2,883,584 B

  pack_weights<<<(NC * D_ + 255) / 256, 256, 0, stream>>>(Wq, Ww, Wk, Wcb);
  proj_kernel<<<ROWS / 64, 256, 0, stream>>>(hs, Wcb, Cb);
  dim3 g(T_ / 128, T_ / 128, B_);
  score_kernel<<<g, 256, 0, stream>>>(Cb, out);
}

// Round 2
// 98.323 us; speedup vs baseline: 2.2148x; 2.2148x over previous
//
#include <hip/hip_runtime.h>
#include <hip/hip_bf16.h>

#define B_ 2
#define T_ 4096
#define D_ 2048
#define H_ 4
#define NC 176            // combined proj cols: 128 q | 32 k | 4 w | 12 pad
#define ROWS (B_ * T_)    // 8192

typedef __attribute__((ext_vector_type(8))) short short8;   // 8 x bf16 (4 VGPRs)
typedef __attribute__((ext_vector_type(4))) float f32x4;
typedef __attribute__((ext_vector_type(4))) float float4v;

__device__ inline unsigned short f2bf(float f) {
  unsigned u = __float_as_uint(f);
  u += 0x7fffu + ((u >> 16) & 1u);   // RNE
  return (unsigned short)(u >> 16);
}
__device__ inline float bf2f(unsigned short s) {
  return __uint_as_float(((unsigned)s) << 16);
}

// ---------------- Kernel 1: pack [Wq; Wk; Ww; 0] into bf16 (176 x 2048) -----
__global__ __launch_bounds__(256) void pack_weights(const float* __restrict__ Wq,
                                                    const float* __restrict__ Ww,
                                                    const float* __restrict__ Wk,
                                                    unsigned short* __restrict__ Wcb) {
  int idx = blockIdx.x * 256 + threadIdx.x;
  if (idx >= NC * D_) return;
  int row = idx / D_, col = idx - row * D_;
  float v = 0.f;
  if (row < 128)       v = Wq[row * D_ + col];
  else if (row < 160)  v = Wk[(row - 128) * D_ + col];
  else if (row < 164)  v = Ww[(row - 160) * D_ + col];
  Wcb[idx] = f2bf(v);
}

// ---------------- Kernel 2: Cb(8192x176 bf16) = bf16(hs) @ Wcb^T ------------
// Split-K across the 4 waves of a block: each block owns ONE 16-row m-tile,
// wave w accumulates K-chunk [w*512, (w+1)*512), LDS reduce, wave 0 writes.
// Grid = 512 blocks -> 2048 waves (8/CU) for latency hiding; A read = 64 MB.
__global__ __launch_bounds__(256) void proj_kernel(const float* __restrict__ hs,
                                                   const unsigned short* __restrict__ Wcb,
                                                   unsigned short* __restrict__ Cb) {
  __shared__ f32x4 red[3][11][64];   // 33,792 B

  int wid  = threadIdx.x >> 6;
  int lane = threadIdx.x & 63;
  int lr = lane & 15, lo = lane >> 4;
  int row0 = blockIdx.x * 16;
  int k0   = wid * 512;

  const float*          ap = hs  + (size_t)(row0 + lr) * D_ + k0 + lo * 8;
  const unsigned short* bp = Wcb + (size_t)lr * D_ + k0 + lo * 8;

  f32x4 acc[11];
#pragma unroll
  for (int n = 0; n < 11; ++n) acc[n] = (f32x4){0.f, 0.f, 0.f, 0.f};

#pragma unroll 4
  for (int kk = 0; kk < 512; kk += 32) {
    float4v f0 = *(const float4v*)(ap + kk);
    float4v f1 = *(const float4v*)(ap + kk + 4);
    short8 a;
#pragma unroll
    for (int i = 0; i < 4; ++i) {
      a[i]     = (short)f2bf(f0[i]);
      a[i + 4] = (short)f2bf(f1[i]);
    }
#pragma unroll
    for (int n = 0; n < 11; ++n) {
      short8 b = *(const short8*)(bp + (size_t)n * 16 * D_ + kk);
      acc[n] = __builtin_amdgcn_mfma_f32_16x16x32_bf16(a, b, acc[n], 0, 0, 0);
    }
  }

  if (wid != 0) {
#pragma unroll
    for (int n = 0; n < 11; ++n) red[wid - 1][n][lane] = acc[n];
  }
  __syncthreads();

  if (wid == 0) {
#pragma unroll
    for (int n = 0; n < 11; ++n) {
      f32x4 r0 = red[0][n][lane], r1 = red[1][n][lane], r2 = red[2][n][lane];
#pragma unroll
      for (int r = 0; r < 4; ++r) acc[n][r] += r0[r] + r1[r] + r2[r];
    }
    int crow = row0 + lo * 4;   // C/D: col = lane&15, row = (lane>>4)*4 + reg
#pragma unroll
    for (int n = 0; n < 11; ++n) {
      int col = n * 16 + lr;
#pragma unroll
      for (int r = 0; r < 4; ++r)
        Cb[(size_t)(crow + r) * NC + col] = f2bf(acc[n][r]);
    }
  }
}

// ---------------- Kernel 3: out[b,t,s] = sum_h w[t,h]*relu(q[t,h,:].k[s,:]) -
// grid (S/128, T/128, B), block 256 (4 waves, 2x2 quadrants of 64x64).
__global__ __launch_bounds__(256) void score_kernel(const unsigned short* __restrict__ Cb,
                                                    float* __restrict__ out) {
  int b = blockIdx.z, tb = blockIdx.y, sb = blockIdx.x;
  int wid  = threadIdx.x >> 6;
  int lane = threadIdx.x & 63;
  int lr = lane & 15, lo = lane >> 4;
  int wm = wid >> 1, wn = wid & 1;
  int t_base = tb * 128 + wm * 64;
  int s_base = sb * 128 + wn * 64;

  const unsigned short* C = Cb + (size_t)b * T_ * NC;
  float* O = out + (size_t)b * T_ * T_;

  // B-frags: k is shared across heads -> only 4 (one per n-tile)
  short8 bf[4];
#pragma unroll
  for (int n = 0; n < 4; ++n)
    bf[n] = *(const short8*)(C + (size_t)(s_base + n * 16 + lr) * NC + 128 + lo * 8);

  const f32x4 zero = (f32x4){0.f, 0.f, 0.f, 0.f};

#pragma unroll
  for (int m = 0; m < 4; ++m) {
    int ta = t_base + m * 16;
    short8 af[H_];
#pragma unroll
    for (int h = 0; h < H_; ++h)
      af[h] = *(const short8*)(C + (size_t)(ta + lr) * NC + h * 32 + lo * 8);

    int tc = ta + lo * 4;
    float wv[4][H_];
#pragma unroll
    for (int r = 0; r < 4; ++r) {
      const unsigned short* wp = C + (size_t)(tc + r) * NC + 160;
#pragma unroll
      for (int h = 0; h < H_; ++h) wv[r][h] = bf2f(wp[h]);
    }

#pragma unroll
    for (int n = 0; n < 4; ++n) {
      f32x4 o = zero;
#pragma unroll
      for (int h = 0; h < H_; ++h) {
        f32x4 c = __builtin_amdgcn_mfma_f32_16x16x32_bf16(af[h], bf[n], zero, 0, 0, 0);
#pragma unroll
        for (int r = 0; r < 4; ++r) o[r] += wv[r][h] * fmaxf(c[r], 0.f);
      }
      int sc = s_base + n * 16 + lr;
#pragma unroll
      for (int r = 0; r < 4; ++r)
        O[(size_t)(tc + r) * T_ + sc] = o[r];
    }
  }
}

// ---------------------------------------------------------------------------
extern "C" void kernel_launch(void* const* d_in, const int* in_sizes, int n_in,
                              void* d_out, int out_size, void* d_ws, size_t ws_size,
                              hipStream_t stream) {
  const float* hs = (const float*)d_in[0];
  const float* Wq = (const float*)d_in[1];
  const float* Ww = (const float*)d_in[2];
  const float* Wk = (const float*)d_in[3];
  float* out = (float*)d_out;

  unsigned short* Wcb = (unsigned short*)d_ws;                      // 720,896 B
  unsigned short* Cb  = (unsigned short*)((char*)d_ws + (1 << 20)); // 2,883,584 B

  pack_weights<<<(NC * D_ + 255) / 256, 256, 0, stream>>>(Wq, Ww, Wk, Wcb);
  proj_kernel<<<ROWS / 16, 256, 0, stream>>>(hs, Wcb, Cb);
  dim3 g(T_ / 128, T_ / 128, B_);
  score_kernel<<<g, 256, 0, stream>>>(Cb, out);
}

// Round 3
// 90.114 us; speedup vs baseline: 2.4166x; 1.0911x over previous
//
#include <hip/hip_runtime.h>
#include <hip/hip_bf16.h>

#define B_ 2
#define T_ 4096
#define D_ 2048
#define H_ 4
#define NC 176            // combined proj cols: 128 q | 32 k | 4 w | 12 pad
#define ROWS (B_ * T_)    // 8192
#define PADW 72           // A_lds row pitch in bf16 (144 B -> 2-way banks)

typedef __attribute__((ext_vector_type(8))) short short8;   // 8 x bf16
typedef __attribute__((ext_vector_type(4))) float f32x4;
typedef __attribute__((ext_vector_type(4))) float float4v;

__device__ inline unsigned short f2bf(float f) {
  unsigned u = __float_as_uint(f);
  u += 0x7fffu + ((u >> 16) & 1u);   // RNE
  return (unsigned short)(u >> 16);
}
__device__ inline float bf2f(unsigned short s) {
  return __uint_as_float(((unsigned)s) << 16);
}

// ---------------- Kernel 1: pack [Wq; Wk; Ww; 0] into bf16 (176 x 2048) -----
__global__ __launch_bounds__(256) void pack_weights(const float* __restrict__ Wq,
                                                    const float* __restrict__ Ww,
                                                    const float* __restrict__ Wk,
                                                    unsigned short* __restrict__ Wcb) {
  int idx = blockIdx.x * 256 + threadIdx.x;
  if (idx >= NC * D_) return;
  int row = idx / D_, col = idx - row * D_;
  float v = 0.f;
  if (row < 128)       v = Wq[row * D_ + col];
  else if (row < 160)  v = Wk[(row - 128) * D_ + col];
  else if (row < 164)  v = Ww[(row - 160) * D_ + col];
  Wcb[idx] = f2bf(v);
}

// ---------------- Kernel 2: Cb(8192x176 bf16) = bf16(hs) @ Wcb^T ------------
// 512 blocks x 8 waves. Block = one 16-row m-tile, full K=2048 (32 steps of
// K=64). Waves split N: wave w owns n-frag w (+ frag 8+w for w<3) -> acc <= 8
// VGPRs, leaving headroom to pipeline B loads. A is staged into LDS as bf16
// by a rotating stager wave with a T14 issue-early/write-late split.
__global__ __launch_bounds__(512) void proj_kernel(const float* __restrict__ hs,
                                                   const unsigned short* __restrict__ Wcb,
                                                   unsigned short* __restrict__ Cb) {
  __shared__ unsigned short A_lds[2][16 * PADW];   // 2 x 2304 B

  int wid  = threadIdx.x >> 6;
  int lane = threadIdx.x & 63;
  int lr = lane & 15, lo = lane >> 4;
  int row0 = blockIdx.x * 16;

  // stager lane mapping: lane -> (row srow, 16-float group scol) of a K=64 slice
  int srow = lane >> 2, scol = lane & 3;
  const float* sp = hs + (size_t)(row0 + srow) * D_ + scol * 16;
  int sdst = srow * PADW + scol * 16;   // bf16 elem index in A_lds[buf]

  int nf = (wid < 3) ? 2 : 1;
  const unsigned short* bp0 = Wcb + (size_t)(wid * 16 + lr) * D_ + lo * 8;
  const unsigned short* bp1 = Wcb + (size_t)((8 + wid) * 16 + lr) * D_ + lo * 8;

  f32x4 acc0 = (f32x4){0.f, 0.f, 0.f, 0.f};
  f32x4 acc1 = (f32x4){0.f, 0.f, 0.f, 0.f};

  float4v pf0, pf1, pf2, pf3;   // pending stage registers (16 floats)

#define ISSUE(S)                                   \
  do {                                             \
    const float* p_ = sp + (S) * 64;               \
    pf0 = *(const float4v*)(p_);                   \
    pf1 = *(const float4v*)(p_ + 4);               \
    pf2 = *(const float4v*)(p_ + 8);               \
    pf3 = *(const float4v*)(p_ + 12);              \
  } while (0)

#define WRITE(BUF)                                                   \
  do {                                                               \
    short8 v0, v1;                                                   \
    v0[0]=(short)f2bf(pf0[0]); v0[1]=(short)f2bf(pf0[1]);            \
    v0[2]=(short)f2bf(pf0[2]); v0[3]=(short)f2bf(pf0[3]);            \
    v0[4]=(short)f2bf(pf1[0]); v0[5]=(short)f2bf(pf1[1]);            \
    v0[6]=(short)f2bf(pf1[2]); v0[7]=(short)f2bf(pf1[3]);            \
    v1[0]=(short)f2bf(pf2[0]); v1[1]=(short)f2bf(pf2[1]);            \
    v1[2]=(short)f2bf(pf2[2]); v1[3]=(short)f2bf(pf2[3]);            \
    v1[4]=(short)f2bf(pf3[0]); v1[5]=(short)f2bf(pf3[1]);            \
    v1[6]=(short)f2bf(pf3[2]); v1[7]=(short)f2bf(pf3[3]);            \
    *(short8*)&A_lds[BUF][sdst]     = v0;                            \
    *(short8*)&A_lds[BUF][sdst + 8] = v1;                            \
  } while (0)

  // prologue: slice 0 issued+written by wave 0; slice 1 issued by wave 1
  if (wid == 0) ISSUE(0);
  if (wid == 1) ISSUE(1);
  if (wid == 0) WRITE(0);
  __syncthreads();

  for (int s = 0; s < 32; ++s) {
    int buf = s & 1;
    if (s + 2 < 32 && wid == ((s + 2) & 7)) ISSUE(s + 2);
    if (s + 1 < 32 && wid == ((s + 1) & 7)) WRITE(buf ^ 1);

    const unsigned short* ab = &A_lds[buf][lr * PADW + lo * 8];
    short8 a0 = *(const short8*)ab;          // k = s*64 + lo*8 .. +7
    short8 a1 = *(const short8*)(ab + 32);   // k = s*64 + 32 + lo*8 .. +7

    short8 b00 = *(const short8*)(bp0 + s * 64);
    short8 b01 = *(const short8*)(bp0 + s * 64 + 32);
    acc0 = __builtin_amdgcn_mfma_f32_16x16x32_bf16(a0, b00, acc0, 0, 0, 0);
    acc0 = __builtin_amdgcn_mfma_f32_16x16x32_bf16(a1, b01, acc0, 0, 0, 0);
    if (nf == 2) {
      short8 b10 = *(const short8*)(bp1 + s * 64);
      short8 b11 = *(const short8*)(bp1 + s * 64 + 32);
      acc1 = __builtin_amdgcn_mfma_f32_16x16x32_bf16(a0, b10, acc1, 0, 0, 0);
      acc1 = __builtin_amdgcn_mfma_f32_16x16x32_bf16(a1, b11, acc1, 0, 0, 0);
    }
    __syncthreads();
  }
#undef ISSUE
#undef WRITE

  // epilogue: C/D layout col = lane&15, row = (lane>>4)*4 + reg
  int crow = row0 + lo * 4;
  {
    int col = wid * 16 + lr;
#pragma unroll
    for (int r = 0; r < 4; ++r)
      Cb[(size_t)(crow + r) * NC + col] = f2bf(acc0[r]);
  }
  if (nf == 2) {
    int col = (8 + wid) * 16 + lr;
#pragma unroll
    for (int r = 0; r < 4; ++r)
      Cb[(size_t)(crow + r) * NC + col] = f2bf(acc1[r]);
  }
}

// ---------------- Kernel 3: out[b,t,s] = sum_h w[t,h]*relu(q[t,h,:].k[s,:]) -
// grid (S/128, T/128, B), block 256 (4 waves, 2x2 quadrants of 64x64).
__global__ __launch_bounds__(256) void score_kernel(const unsigned short* __restrict__ Cb,
                                                    float* __restrict__ out) {
  int b = blockIdx.z, tb = blockIdx.y, sb = blockIdx.x;
  int wid  = threadIdx.x >> 6;
  int lane = threadIdx.x & 63;
  int lr = lane & 15, lo = lane >> 4;
  int wm = wid >> 1, wn = wid & 1;
  int t_base = tb * 128 + wm * 64;
  int s_base = sb * 128 + wn * 64;

  const unsigned short* C = Cb + (size_t)b * T_ * NC;
  float* O = out + (size_t)b * T_ * T_;

  // B-frags: k is shared across heads -> only 4 (one per n-tile)
  short8 bf[4];
#pragma unroll
  for (int n = 0; n < 4; ++n)
    bf[n] = *(const short8*)(C + (size_t)(s_base + n * 16 + lr) * NC + 128 + lo * 8);

  const f32x4 zero = (f32x4){0.f, 0.f, 0.f, 0.f};

#pragma unroll
  for (int m = 0; m < 4; ++m) {
    int ta = t_base + m * 16;
    short8 af[H_];
#pragma unroll
    for (int h = 0; h < H_; ++h)
      af[h] = *(const short8*)(C + (size_t)(ta + lr) * NC + h * 32 + lo * 8);

    int tc = ta + lo * 4;
    float wv[4][H_];
#pragma unroll
    for (int r = 0; r < 4; ++r) {
      const unsigned short* wp = C + (size_t)(tc + r) * NC + 160;
#pragma unroll
      for (int h = 0; h < H_; ++h) wv[r][h] = bf2f(wp[h]);
    }

#pragma unroll
    for (int n = 0; n < 4; ++n) {
      f32x4 o = zero;
#pragma unroll
      for (int h = 0; h < H_; ++h) {
        f32x4 c = __builtin_amdgcn_mfma_f32_16x16x32_bf16(af[h], bf[n], zero, 0, 0, 0);
#pragma unroll
        for (int r = 0; r < 4; ++r) o[r] += wv[r][h] * fmaxf(c[r], 0.f);
      }
      int sc = s_base + n * 16 + lr;
#pragma unroll
      for (int r = 0; r < 4; ++r)
        O[(size_t)(tc + r) * T_ + sc] = o[r];
    }
  }
}

// ---------------------------------------------------------------------------
extern "C" void kernel_launch(void* const* d_in, const int* in_sizes, int n_in,
                              void* d_out, int out_size, void* d_ws, size_t ws_size,
                              hipStream_t stream) {
  const float* hs = (const float*)d_in[0];
  const float* Wq = (const float*)d_in[1];
  const float* Ww = (const float*)d_in[2];
  const float* Wk = (const float*)d_in[3];
  float* out = (float*)d_out;

  unsigned short* Wcb = (unsigned short*)d_ws;                      // 720,896 B
  unsigned short* Cb  = (unsigned short*)((char*)d_ws + (1 << 20)); // 2,883,584 B

  pack_weights<<<(NC * D_ + 255) / 256, 256, 0, stream>>>(Wq, Ww, Wk, Wcb);
  proj_kernel<<<ROWS / 16, 512, 0, stream>>>(hs, Wcb, Cb);
  dim3 g(T_ / 128, T_ / 128, B_);
  score_kernel<<<g, 256, 0, stream>>>(Cb, out);
}

// Round 4
// 88.839 us; speedup vs baseline: 2.4513x; 1.0144x over previous
//
#include <hip/hip_runtime.h>
#include <hip/hip_bf16.h>

#define B_ 2
#define T_ 4096
#define D_ 2048
#define H_ 4
#define NC 176            // combined proj cols: 128 q | 32 k | 4 w | 12 pad
#define ROWS (B_ * T_)    // 8192

typedef __attribute__((ext_vector_type(8))) short short8;   // 8 x bf16
typedef __attribute__((ext_vector_type(4))) float f32x4;
typedef __attribute__((ext_vector_type(4))) float float4v;

__device__ inline unsigned short f2bf(float f) {
  unsigned u = __float_as_uint(f);
  u += 0x7fffu + ((u >> 16) & 1u);   // RNE
  return (unsigned short)(u >> 16);
}
__device__ inline float bf2f(unsigned short s) {
  return __uint_as_float(((unsigned)s) << 16);
}

// ---------------- Kernel 1: pack [Wq; Wk; Ww; 0] into bf16 (176 x 2048) -----
__global__ __launch_bounds__(256) void pack_weights(const float* __restrict__ Wq,
                                                    const float* __restrict__ Ww,
                                                    const float* __restrict__ Wk,
                                                    unsigned short* __restrict__ Wcb) {
  int idx = blockIdx.x * 256 + threadIdx.x;
  if (idx >= NC * D_) return;
  int row = idx / D_, col = idx - row * D_;
  float v = 0.f;
  if (row < 128)       v = Wq[row * D_ + col];
  else if (row < 160)  v = Wk[(row - 128) * D_ + col];
  else if (row < 164)  v = Ww[(row - 160) * D_ + col];
  Wcb[idx] = f2bf(v);
}

// ---------------- Kernel 2: Cb(8192x176 bf16) = bf16(hs) @ Wcb^T ------------
// Split-K across the 4 waves (wave w owns K-chunk [w*512,(w+1)*512)), one
// 16-row m-tile per block, LDS reduce at the end. Hot loop fully unrolled
// (16 steps of K=32) with explicit register double-buffering: all 13 loads
// of step s+1 are issued before the 11 MFMAs of step s. No barriers in loop.
__global__ __launch_bounds__(256) void proj_kernel(const float* __restrict__ hs,
                                                   const unsigned short* __restrict__ Wcb,
                                                   unsigned short* __restrict__ Cb) {
  __shared__ f32x4 red[3][11][64];   // 33,792 B

  int wid  = threadIdx.x >> 6;
  int lane = threadIdx.x & 63;
  int lr = lane & 15, lo = lane >> 4;
  int row0 = blockIdx.x * 16;
  int k0   = wid * 512;

  const float*          ap = hs  + (size_t)(row0 + lr) * D_ + k0 + lo * 8;
  const unsigned short* bp = Wcb + (size_t)lr * D_ + k0 + lo * 8;

  f32x4 acc[11];
#pragma unroll
  for (int n = 0; n < 11; ++n) acc[n] = (f32x4){0.f, 0.f, 0.f, 0.f};

  float4v A0[2], A1[2];
  short8  Bv[2][11];

  // prologue: load step 0
  A0[0] = *(const float4v*)(ap);
  A1[0] = *(const float4v*)(ap + 4);
#pragma unroll
  for (int n = 0; n < 11; ++n)
    Bv[0][n] = *(const short8*)(bp + (size_t)n * 16 * D_);

#pragma unroll
  for (int s = 0; s < 16; ++s) {
    const int cur = s & 1, nxt = cur ^ 1;
    if (s < 15) {   // issue next-step loads BEFORE this step's MFMAs
      A0[nxt] = *(const float4v*)(ap + (s + 1) * 32);
      A1[nxt] = *(const float4v*)(ap + (s + 1) * 32 + 4);
#pragma unroll
      for (int n = 0; n < 11; ++n)
        Bv[nxt][n] = *(const short8*)(bp + (size_t)n * 16 * D_ + (s + 1) * 32);
    }
    short8 a;
#pragma unroll
    for (int i = 0; i < 4; ++i) {
      a[i]     = (short)f2bf(A0[cur][i]);
      a[i + 4] = (short)f2bf(A1[cur][i]);
    }
#pragma unroll
    for (int n = 0; n < 11; ++n)
      acc[n] = __builtin_amdgcn_mfma_f32_16x16x32_bf16(a, Bv[cur][n], acc[n], 0, 0, 0);
  }

  if (wid != 0) {
#pragma unroll
    for (int n = 0; n < 11; ++n) red[wid - 1][n][lane] = acc[n];
  }
  __syncthreads();

  if (wid == 0) {
#pragma unroll
    for (int n = 0; n < 11; ++n) {
      f32x4 r0 = red[0][n][lane], r1 = red[1][n][lane], r2 = red[2][n][lane];
#pragma unroll
      for (int r = 0; r < 4; ++r) acc[n][r] += r0[r] + r1[r] + r2[r];
    }
    int crow = row0 + lo * 4;   // C/D: col = lane&15, row = (lane>>4)*4 + reg
#pragma unroll
    for (int n = 0; n < 11; ++n) {
      int col = n * 16 + lr;
#pragma unroll
      for (int r = 0; r < 4; ++r)
        Cb[(size_t)(crow + r) * NC + col] = f2bf(acc[n][r]);
    }
  }
}

// ---------------- Kernel 3: out[b,t,s] = sum_h w[t,h]*relu(q[t,h,:].k[s,:]) -
// grid (S/128, T/128, B), block 256 (4 waves, 2x2 quadrants of 64x64).
__global__ __launch_bounds__(256) void score_kernel(const unsigned short* __restrict__ Cb,
                                                    float* __restrict__ out) {
  int b = blockIdx.z, tb = blockIdx.y, sb = blockIdx.x;
  int wid  = threadIdx.x >> 6;
  int lane = threadIdx.x & 63;
  int lr = lane & 15, lo = lane >> 4;
  int wm = wid >> 1, wn = wid & 1;
  int t_base = tb * 128 + wm * 64;
  int s_base = sb * 128 + wn * 64;

  const unsigned short* C = Cb + (size_t)b * T_ * NC;
  float* O = out + (size_t)b * T_ * T_;

  // B-frags: k is shared across heads -> only 4 (one per n-tile)
  short8 bf[4];
#pragma unroll
  for (int n = 0; n < 4; ++n)
    bf[n] = *(const short8*)(C + (size_t)(s_base + n * 16 + lr) * NC + 128 + lo * 8);

  const f32x4 zero = (f32x4){0.f, 0.f, 0.f, 0.f};

#pragma unroll
  for (int m = 0; m < 4; ++m) {
    int ta = t_base + m * 16;
    short8 af[H_];
#pragma unroll
    for (int h = 0; h < H_; ++h)
      af[h] = *(const short8*)(C + (size_t)(ta + lr) * NC + h * 32 + lo * 8);

    int tc = ta + lo * 4;
    float wv[4][H_];
#pragma unroll
    for (int r = 0; r < 4; ++r) {
      const unsigned short* wp = C + (size_t)(tc + r) * NC + 160;
#pragma unroll
      for (int h = 0; h < H_; ++h) wv[r][h] = bf2f(wp[h]);
    }

#pragma unroll
    for (int n = 0; n < 4; ++n) {
      f32x4 o = zero;
#pragma unroll
      for (int h = 0; h < H_; ++h) {
        f32x4 c = __builtin_amdgcn_mfma_f32_16x16x32_bf16(af[h], bf[n], zero, 0, 0, 0);
#pragma unroll
        for (int r = 0; r < 4; ++r) o[r] += wv[r][h] * fmaxf(c[r], 0.f);
      }
      int sc = s_base + n * 16 + lr;
#pragma unroll
      for (int r = 0; r < 4; ++r)
        O[(size_t)(tc + r) * T_ + sc] = o[r];
    }
  }
}

// ---------------------------------------------------------------------------
extern "C" void kernel_launch(void* const* d_in, const int* in_sizes, int n_in,
                              void* d_out, int out_size, void* d_ws, size_t ws_size,
                              hipStream_t stream) {
  const float* hs = (const float*)d_in[0];
  const float* Wq = (const float*)d_in[1];
  const float* Ww = (const float*)d_in[2];
  const float* Wk = (const float*)d_in[3];
  float* out = (float*)d_out;

  unsigned short* Wcb = (unsigned short*)d_ws;                      // 720,896 B
  unsigned short* Cb  = (unsigned short*)((char*)d_ws + (1 << 20)); // 2,883,584 B

  pack_weights<<<(NC * D_ + 255) / 256, 256, 0, stream>>>(Wq, Ww, Wk, Wcb);
  proj_kernel<<<ROWS / 16, 256, 0, stream>>>(hs, Wcb, Cb);
  dim3 g(T_ / 128, T_ / 128, B_);
  score_kernel<<<g, 256, 0, stream>>>(Cb, out);
}

// Round 5
// 62.246 us; speedup vs baseline: 3.4985x; 1.4272x over previous
//
#include <hip/hip_runtime.h>
#include <hip/hip_bf16.h>

#define B_ 2
#define T_ 4096
#define D_ 2048
#define H_ 4
#define NC 176            // combined proj cols: 128 q | 32 k | 4 w | 12 pad
#define ROWS (B_ * T_)    // 8192
#define NT 11             // n-tiles of 16 rows
#define TILE_E (16 * NC)  // 2816 elems per 16-row tile of Cb2
#define WTILE_E (16 * D_) // 32768 elems per 16-row n-tile of Wcb2

typedef __attribute__((ext_vector_type(8))) short short8;   // 8 x bf16
typedef __attribute__((ext_vector_type(4))) short short4v;  // 4 x bf16
typedef __attribute__((ext_vector_type(4))) float f32x4;
typedef __attribute__((ext_vector_type(4))) float float4v;

__device__ inline unsigned short f2bf(float f) {
  unsigned u = __float_as_uint(f);
  u += 0x7fffu + ((u >> 16) & 1u);   // RNE
  return (unsigned short)(u >> 16);
}
__device__ inline float bf2f(unsigned short s) {
  return __uint_as_float(((unsigned)s) << 16);
}

// ---------------- Kernel 1: pack weights into octet-tiled bf16 --------------
// Wcb2 layout: E(n, r, k) = n*32768 + (k>>3)*128 + r*8 + (k&7)
// where combined row R = n*16 + r  (R: 0-127 q | 128-159 k | 160-163 w | pad)
// This makes a wave's MFMA B-fragment load 1024 CONTIGUOUS bytes.
__global__ __launch_bounds__(256) void pack_weights(const float* __restrict__ Wq,
                                                    const float* __restrict__ Ww,
                                                    const float* __restrict__ Wk,
                                                    unsigned short* __restrict__ Wcb) {
  int idx = blockIdx.x * 256 + threadIdx.x;
  if (idx >= NC * D_) return;
  int row = idx / D_, col = idx - row * D_;
  float v = 0.f;
  if (row < 128)       v = Wq[row * D_ + col];
  else if (row < 160)  v = Wk[(row - 128) * D_ + col];
  else if (row < 164)  v = Ww[(row - 160) * D_ + col];
  int n = row >> 4, r = row & 15;
  size_t dst = (size_t)n * WTILE_E + (size_t)(col >> 3) * 128 + r * 8 + (col & 7);
  Wcb[dst] = f2bf(v);
}

// ---------------- Kernel 2: Cb2 = bf16(hs) @ Wcb^T (tiled layouts) ----------
// Split-K across 4 waves (wave w: K in [w*512,(w+1)*512)), one 16-row m-tile
// per block, register double-buffer, fully unrolled 16-step loop, LDS reduce.
// B-frag (n, s) now sits at bbase + n*WTILE_E + s*512 -> coalesced 1KB load.
__global__ __launch_bounds__(256) void proj_kernel(const float* __restrict__ hs,
                                                   const unsigned short* __restrict__ Wcb,
                                                   unsigned short* __restrict__ Cb) {
  __shared__ f32x4 red[3][11][64];   // 33,792 B

  int wid  = threadIdx.x >> 6;
  int lane = threadIdx.x & 63;
  int lr = lane & 15, lo = lane >> 4;
  int row0 = blockIdx.x * 16;
  int k0   = wid * 512;

  const float*          ap    = hs  + (size_t)(row0 + lr) * D_ + k0 + lo * 8;
  const unsigned short* bbase = Wcb + (size_t)k0 * 16 + lo * 128 + lr * 8;

  f32x4 acc[11];
#pragma unroll
  for (int n = 0; n < 11; ++n) acc[n] = (f32x4){0.f, 0.f, 0.f, 0.f};

  float4v A0[2], A1[2];
  short8  Bv[2][11];

  // prologue: load step 0
  A0[0] = *(const float4v*)(ap);
  A1[0] = *(const float4v*)(ap + 4);
#pragma unroll
  for (int n = 0; n < 11; ++n)
    Bv[0][n] = *(const short8*)(bbase + (size_t)n * WTILE_E);

#pragma unroll
  for (int s = 0; s < 16; ++s) {
    const int cur = s & 1, nxt = cur ^ 1;
    if (s < 15) {   // issue next-step loads BEFORE this step's MFMAs
      A0[nxt] = *(const float4v*)(ap + (s + 1) * 32);
      A1[nxt] = *(const float4v*)(ap + (s + 1) * 32 + 4);
#pragma unroll
      for (int n = 0; n < 11; ++n)
        Bv[nxt][n] = *(const short8*)(bbase + (size_t)n * WTILE_E + (s + 1) * 512);
    }
    short8 a;
#pragma unroll
    for (int i = 0; i < 4; ++i) {
      a[i]     = (short)f2bf(A0[cur][i]);
      a[i + 4] = (short)f2bf(A1[cur][i]);
    }
#pragma unroll
    for (int n = 0; n < 11; ++n)
      acc[n] = __builtin_amdgcn_mfma_f32_16x16x32_bf16(a, Bv[cur][n], acc[n], 0, 0, 0);
  }

  if (wid != 0) {
#pragma unroll
    for (int n = 0; n < 11; ++n) red[wid - 1][n][lane] = acc[n];
  }
  __syncthreads();

  if (wid == 0) {
#pragma unroll
    for (int n = 0; n < 11; ++n) {
      f32x4 r0 = red[0][n][lane], r1 = red[1][n][lane], r2 = red[2][n][lane];
#pragma unroll
      for (int r = 0; r < 4; ++r) acc[n][r] += r0[r] + r1[r] + r2[r];
    }
    // Cb2 layout: F(t,c) = (t>>4)*TILE_E + (c>>3)*128 + (t&15)*8 + (c&7)
    // here t = row0 + lo*4 + r (tile row0>>4), c = n*16 + lr.
    unsigned short* cb = Cb + (size_t)(row0 >> 4) * TILE_E + (lr & 7);
#pragma unroll
    for (int n = 0; n < 11; ++n) {
      int oct = n * 2 + (lr >> 3);
#pragma unroll
      for (int r = 0; r < 4; ++r)
        cb[oct * 128 + (lo * 4 + r) * 8] = f2bf(acc[n][r]);
    }
  }
}

// ---------------- Kernel 3: out[b,t,s] = sum_h w[t,h]*relu(q[t,h,:].k[s,:]) -
// grid (S/128, T/128, B), block 256 (4 waves, 2x2 quadrants of 64x64).
// All Cb2 fragment reads are coalesced 1KB wave-loads in the tiled layout.
__global__ __launch_bounds__(256) void score_kernel(const unsigned short* __restrict__ Cb,
                                                    float* __restrict__ out) {
  int b = blockIdx.z, tb = blockIdx.y, sb = blockIdx.x;
  int wid  = threadIdx.x >> 6;
  int lane = threadIdx.x & 63;
  int lr = lane & 15, lo = lane >> 4;
  int wm = wid >> 1, wn = wid & 1;
  int t_base = tb * 128 + wm * 64;
  int s_base = sb * 128 + wn * 64;

  const unsigned short* C2 = Cb + (size_t)b * (T_ / 16) * TILE_E;
  float* O = out + (size_t)b * T_ * T_;

  // B-frags (k part, cols 128..159 -> octet 16+lo): shared across heads
  short8 bf[4];
#pragma unroll
  for (int n = 0; n < 4; ++n)
    bf[n] = *(const short8*)(C2 + (size_t)((s_base >> 4) + n) * TILE_E +
                             (16 + lo) * 128 + lr * 8);

  const f32x4 zero = (f32x4){0.f, 0.f, 0.f, 0.f};

#pragma unroll
  for (int m = 0; m < 4; ++m) {
    const unsigned short* Ct = C2 + (size_t)((t_base >> 4) + m) * TILE_E;

    short8 af[H_];   // q part: cols h*32..+31 -> octet h*4+lo
#pragma unroll
    for (int h = 0; h < H_; ++h)
      af[h] = *(const short8*)(Ct + (h * 4 + lo) * 128 + lr * 8);

    // w part: cols 160..163 -> octet 20, elem h; row inner = lo*4+r
    float wv[4][H_];
    const unsigned short* wp = Ct + 20 * 128 + lo * 32;
#pragma unroll
    for (int r = 0; r < 4; ++r) {
      short4v w4 = *(const short4v*)(wp + r * 8);
#pragma unroll
      for (int h = 0; h < H_; ++h) wv[r][h] = bf2f((unsigned short)w4[h]);
    }

    int tc = t_base + m * 16 + lo * 4;
#pragma unroll
    for (int n = 0; n < 4; ++n) {
      f32x4 o = zero;
#pragma unroll
      for (int h = 0; h < H_; ++h) {
        f32x4 c = __builtin_amdgcn_mfma_f32_16x16x32_bf16(af[h], bf[n], zero, 0, 0, 0);
#pragma unroll
        for (int r = 0; r < 4; ++r) o[r] += wv[r][h] * fmaxf(c[r], 0.f);
      }
      int sc = s_base + n * 16 + lr;
#pragma unroll
      for (int r = 0; r < 4; ++r)
        O[(size_t)(tc + r) * T_ + sc] = o[r];
    }
  }
}

// ---------------------------------------------------------------------------
extern "C" void kernel_launch(void* const* d_in, const int* in_sizes, int n_in,
                              void* d_out, int out_size, void* d_ws, size_t ws_size,
                              hipStream_t stream) {
  const float* hs = (const float*)d_in[0];
  const float* Wq = (const float*)d_in[1];
  const float* Ww = (const float*)d_in[2];
  const float* Wk = (const float*)d_in[3];
  float* out = (float*)d_out;

  unsigned short* Wcb = (unsigned short*)d_ws;                      // 720,896 B
  unsigned short* Cb  = (unsigned short*)((char*)d_ws + (1 << 20)); // 2,883,584 B

  pack_weights<<<(NC * D_ + 255) / 256, 256, 0, stream>>>(Wq, Ww, Wk, Wcb);
  proj_kernel<<<ROWS / 16, 256, 0, stream>>>(hs, Wcb, Cb);
  dim3 g(T_ / 128, T_ / 128, B_);
  score_kernel<<<g, 256, 0, stream>>>(Cb, out);
}